// Round 10
// baseline (306.863 us; speedup 1.0000x reference)
//
#include <hip/hip_runtime.h>
#include <hip/hip_bf16.h>

// GCN 2-layer forward, fp32 I/O. Packed 4B edge records, fixed-capacity
// bucketed CSR build (per-node atomics in LDS, merged hist+scan+scatter),
// csr = src-only 4B (pulls re-gather dinv from L2-resident table),
// bf16 h + agg1 storage, MFMA bf16 GEMMs, one-wave-per-node pulls.
// Pipeline:
//  1) k_prep: W1,W2 -> bf16 transposed; bcur[b] = b*CAP
//  2) k_bucket: partition packed {src,dloc} by dst>>9 into ebuf
//  3) k_bcsr:  per-bucket LDS stage -> hist -> scan -> deg/dinv/row_ptr
//              -> LDS-cursor scatter -> csr4 = src
//  4) h1 = x @ W1 -> bf16                          (k_gemm1, MFMA)
//  5) agg1 = D^-1/2 (A+I) D^-1/2 h1 -> bf16        (k_pull128)
//  6) h2 = relu(agg1 + b1) @ W2 -> bf16            (k_gemm2, MFMA)
//  7) out = aggregate(h2) + b2 -> fp32             (k_pull64)

typedef short short8v __attribute__((ext_vector_type(8)));   // 8 bf16 (4 VGPRs)
typedef float f32x4   __attribute__((ext_vector_type(4)));   // MFMA acc

#define BSHIFT 9           // bucket = dst >> 9 (span 512 nodes)
#define BSIZE  512
#define CAPSH  14          // per-bucket capacity 16384 (mean 8163, >40 sigma)
#define CAP    (1 << CAPSH)

// RNE fp32 -> bf16 (finite inputs)
__device__ __forceinline__ short f2bf(float f) {
    unsigned u = __float_as_uint(f);
    return (short)((u + 0x7fffu + ((u >> 16) & 1u)) >> 16);
}
__device__ __forceinline__ unsigned pack2bf(float a, float b) {
    return (unsigned)(unsigned short)f2bf(a) | ((unsigned)(unsigned short)f2bf(b) << 16);
}
__device__ __forceinline__ float bflo(unsigned u) { return __uint_as_float(u << 16); }
__device__ __forceinline__ float bfhi(unsigned u) { return __uint_as_float(u & 0xffff0000u); }

// ---- W prep + bucket-cursor init (one launch) ----
__global__ void k_prep(const float* __restrict__ W1, const float* __restrict__ W2,
                       short* __restrict__ w1t, short* __restrict__ w2t,
                       int* __restrict__ bcur, int nbuck) {
    int b = blockIdx.x;
    int t = threadIdx.x;
    if (b == gridDim.x - 1) {                 // last block: init bucket cursors
        if (t < nbuck) bcur[t] = t << CAPSH;
        return;
    }
    int i = b * 256 + t;                      // 96 blocks cover 24576 elems
    if (i < 128 * 128) {
        int n = i >> 7, k = i & 127;
        w1t[i] = f2bf(W1[k * 128 + n]);
    } else {
        int j = i - 128 * 128;
        int n = j >> 7, k = j & 127;
        w2t[j] = f2bf(W2[k * 64 + n]);
    }
}

// ---- partition edges into packed ebuf: entry = (src<<9) | (dst&511) ----
__global__ __launch_bounds__(256) void k_bucket(const int* __restrict__ src,
                                                const int* __restrict__ dst,
                                                int* __restrict__ bcur,
                                                unsigned* __restrict__ ebuf,
                                                int E, int nbuck) {
    __shared__ int sdst[4096];
    __shared__ int ssrc[4096];
    __shared__ int hist[256];
    __shared__ int base[256];
    int t = threadIdx.x;
    int e0 = blockIdx.x * 4096;
    for (int i = t; i < nbuck; i += 256) hist[i] = 0;
    for (int i = 0; i < 16; ++i) {                  // single global read
        int k = i * 256 + t;
        int e = e0 + k;
        sdst[k] = (e < E) ? dst[e] : -1;
        ssrc[k] = (e < E) ? src[e] : 0;
    }
    __syncthreads();
    for (int i = 0; i < 16; ++i) {                  // pass 1: LDS histogram
        int d = sdst[i * 256 + t];
        if (d >= 0) atomicAdd(&hist[d >> BSHIFT], 1);
    }
    __syncthreads();
    for (int b = t; b < nbuck; b += 256) {          // pass 2: reserve chunks
        int c = hist[b];
        base[b] = c ? atomicAdd(&bcur[b], c) : 0;
        hist[b] = 0;
    }
    __syncthreads();
    for (int i = 0; i < 16; ++i) {                  // pass 3: grouped writes
        int k = i * 256 + t;
        int d = sdst[k];
        if (d >= 0) {
            int bk = d >> BSHIFT;
            int off = atomicAdd(&hist[bk], 1);
            ebuf[base[bk] + off] = ((unsigned)ssrc[k] << BSHIFT) | (unsigned)(d & (BSIZE - 1));
        }
    }
}

// ---- per-bucket merged: LDS stage -> hist -> scan -> deg/dinv/row_ptr
//      -> LDS-cursor scatter -> csr4 = src ----
__global__ __launch_bounds__(BSIZE) void k_bcsr(const unsigned* __restrict__ ebuf,
                                                const int* __restrict__ bcur,
                                                int* __restrict__ deg,
                                                int* __restrict__ row_ptr,
                                                float* __restrict__ dinv,
                                                unsigned* __restrict__ csr4, int n) {
    __shared__ unsigned edges[CAP];    // 64 KB (one block/CU; occupancy moot)
    __shared__ int hist[BSIZE];
    __shared__ int s[BSIZE];
    __shared__ int cur[BSIZE];
    int b = blockIdx.x;
    int t = threadIdx.x;
    hist[t] = 0;
    __syncthreads();
    int base = b << CAPSH;
    int cnt  = bcur[b] - base;
    int lo = b << BSHIFT;
    for (int k = t; k < cnt; k += BSIZE) {          // stage + LDS hist
        unsigned e = ebuf[base + k];
        edges[k] = e;
        atomicAdd(&hist[e & (BSIZE - 1)], 1);
    }
    __syncthreads();
    int v = hist[t];
    s[t] = v;
    __syncthreads();
    for (int off = 1; off < BSIZE; off <<= 1) {     // inclusive scan
        int add = (t >= off) ? s[t - off] : 0;
        __syncthreads();
        s[t] += add;
        __syncthreads();
    }
    int rp = base + s[t] - v;                       // padded-CSR offset
    cur[t] = rp;
    int node = lo + t;
    if (node < n) {
        deg[node]     = v;
        row_ptr[node] = rp;
        dinv[node]    = rsqrtf((float)(v + 1));
    }
    __syncthreads();
    for (int k = t; k < cnt; k += BSIZE) {          // scatter src -> csr4
        unsigned e = edges[k];
        int pos = atomicAdd(&cur[e & (BSIZE - 1)], 1);
        csr4[pos] = e >> BSHIFT;
    }
}

// ---- MFMA GEMM1: h[64rows/block,128] = bf16(x) @ bf16(W1), 256 thr ----
#define LDP 136
__global__ __launch_bounds__(256) void k_gemm1(const float* __restrict__ x,
                                               const short* __restrict__ w1t,
                                               short* __restrict__ h, int nrows) {
    __shared__ short xs[64 * LDP];
    __shared__ short wt[128 * LDP];
    int t = threadIdx.x;
    int row0 = blockIdx.x * 64;
    for (int i = 0; i < 16; ++i) {
        int idx = t + i * 256;
        int r = idx >> 5, c4 = idx & 31;
        float4 v = make_float4(0.f, 0.f, 0.f, 0.f);
        if (row0 + r < nrows) v = ((const float4*)x)[(size_t)(row0 + r) * 32 + c4];
        short4 o = make_short4(f2bf(v.x), f2bf(v.y), f2bf(v.z), f2bf(v.w));
        *(short4*)&xs[r * LDP + c4 * 4] = o;
    }
    for (int i = 0; i < 16; ++i) {
        int idx = t + i * 256;
        int n = idx >> 5, c4 = idx & 31;
        *(short4*)&wt[n * LDP + c4 * 4] = ((const short4*)w1t)[idx];
    }
    __syncthreads();
    int wave = t >> 6, lane = t & 63;
    int quad = lane >> 4, c = lane & 15;
    int m0 = wave * 16;
    f32x4 acc[8] = {};
    #pragma unroll
    for (int kc = 0; kc < 4; ++kc) {
        short8v a = *(const short8v*)&xs[(m0 + c) * LDP + kc * 32 + quad * 8];
        #pragma unroll
        for (int nt = 0; nt < 8; ++nt) {
            short8v b = *(const short8v*)&wt[(nt * 16 + c) * LDP + kc * 32 + quad * 8];
            acc[nt] = __builtin_amdgcn_mfma_f32_16x16x32_bf16(a, b, acc[nt], 0, 0, 0);
        }
    }
    #pragma unroll
    for (int nt = 0; nt < 8; ++nt)
        #pragma unroll
        for (int r = 0; r < 4; ++r) {
            int row = row0 + m0 + quad * 4 + r;
            if (row < nrows) h[(size_t)row * 128 + nt * 16 + c] = f2bf(acc[nt][r]);
        }
}

// ---- MFMA GEMM2: h2[64rows,64] = bf16(relu(bf16agg + b1)) @ bf16(W2) ----
__global__ __launch_bounds__(256) void k_gemm2(const unsigned* __restrict__ aggb, // bf16x2
                                               const float* __restrict__ b1,
                                               const short* __restrict__ w2t,
                                               short* __restrict__ h2, int nrows) {
    __shared__ short xs[64 * LDP];
    __shared__ short wt[64 * LDP];
    int t = threadIdx.x;
    int row0 = blockIdx.x * 64;
    for (int i = 0; i < 16; ++i) {                    // 64 rows x 64 bf16-pairs
        int idx = t + i * 256;
        int r = idx >> 6, cp = idx & 63;
        unsigned o = 0;
        if (row0 + r < nrows) {
            unsigned u = aggb[(size_t)(row0 + r) * 64 + cp];
            float2 bb = ((const float2*)b1)[cp];
            float vx = fmaxf(bflo(u) + bb.x, 0.f);
            float vy = fmaxf(bfhi(u) + bb.y, 0.f);
            o = pack2bf(vx, vy);
        }
        *(unsigned*)&xs[r * LDP + cp * 2] = o;
    }
    for (int i = 0; i < 8; ++i) {
        int idx = t + i * 256;
        int n = idx >> 5, c4 = idx & 31;
        *(short4*)&wt[n * LDP + c4 * 4] = ((const short4*)w2t)[idx];
    }
    __syncthreads();
    int wave = t >> 6, lane = t & 63;
    int quad = lane >> 4, c = lane & 15;
    int m0 = wave * 16;
    f32x4 acc[4] = {};
    #pragma unroll
    for (int kc = 0; kc < 4; ++kc) {
        short8v av = *(const short8v*)&xs[(m0 + c) * LDP + kc * 32 + quad * 8];
        #pragma unroll
        for (int nt = 0; nt < 4; ++nt) {
            short8v b = *(const short8v*)&wt[(nt * 16 + c) * LDP + kc * 32 + quad * 8];
            acc[nt] = __builtin_amdgcn_mfma_f32_16x16x32_bf16(av, b, acc[nt], 0, 0, 0);
        }
    }
    #pragma unroll
    for (int nt = 0; nt < 4; ++nt)
        #pragma unroll
        for (int r = 0; r < 4; ++r) {
            int row = row0 + m0 + quad * 4 + r;
            if (row < nrows) h2[(size_t)row * 64 + nt * 16 + c] = f2bf(acc[nt][r]);
        }
}

// pull aggregation, 128 bf16 feats -> bf16 agg. One wave/node (scalar csr
// path via readfirstlane); dinv[src] gathered from L2-resident 400 KB table.
__global__ __launch_bounds__(256) void k_pull128(const unsigned short* __restrict__ h,
                                                 const int* __restrict__ row_ptr,
                                                 const int* __restrict__ deg,
                                                 const unsigned* __restrict__ csr4,
                                                 const float* __restrict__ dinv,
                                                 unsigned* __restrict__ aggb, int n) {
    int wave = (blockIdx.x * 256 + threadIdx.x) >> 6;
    int lane = threadIdx.x & 63;
    if (wave >= n) return;
    int i = __builtin_amdgcn_readfirstlane(wave);
    float di = dinv[i];
    float2 acc;
    {
        unsigned u = ((const unsigned*)(h + (size_t)i * 128))[lane];
        float w = di * di;
        acc.x = bflo(u) * w;
        acc.y = bfhi(u) * w;
    }
    int beg = row_ptr[i];
    int cnt = deg[i];
    int k = 0;
    for (; k + 8 <= cnt; k += 8) {
        unsigned sid[8];
        float ds[8];
        unsigned g[8];
        #pragma unroll
        for (int j = 0; j < 8; ++j) sid[j] = csr4[beg + k + j];
        #pragma unroll
        for (int j = 0; j < 8; ++j) ds[j] = dinv[sid[j]];
        #pragma unroll
        for (int j = 0; j < 8; ++j)
            g[j] = ((const unsigned*)(h + (size_t)sid[j] * 128))[lane];
        #pragma unroll
        for (int j = 0; j < 8; ++j) {
            float nr = di * ds[j];
            acc.x += bflo(g[j]) * nr;
            acc.y += bfhi(g[j]) * nr;
        }
    }
    for (; k < cnt; ++k) {
        unsigned sid = csr4[beg + k];
        float nr = di * dinv[sid];
        unsigned g = ((const unsigned*)(h + (size_t)sid * 128))[lane];
        acc.x += bflo(g) * nr;
        acc.y += bfhi(g) * nr;
    }
    aggb[(size_t)i * 64 + lane] = pack2bf(acc.x, acc.y);
}

// pull aggregation, 64 bf16 feats, fused +b2 -> out (fp32). One wave/node.
__global__ __launch_bounds__(256) void k_pull64(const unsigned short* __restrict__ h,
                                                const int* __restrict__ row_ptr,
                                                const int* __restrict__ deg,
                                                const unsigned* __restrict__ csr4,
                                                const float* __restrict__ dinv,
                                                const float* __restrict__ b2,
                                                float* __restrict__ out, int n) {
    int wave = (blockIdx.x * 256 + threadIdx.x) >> 6;
    int lane = threadIdx.x & 63;
    if (wave >= n) return;
    int i = __builtin_amdgcn_readfirstlane(wave);
    float di = dinv[i];
    float acc = bflo((unsigned)h[(size_t)i * 64 + lane] << 16 >> 16 << 16) * 0.0f; // (unused)
    {
        unsigned u = h[(size_t)i * 64 + lane];
        acc = __uint_as_float(u << 16) * di * di;
    }
    int beg = row_ptr[i];
    int cnt = deg[i];
    int k = 0;
    for (; k + 8 <= cnt; k += 8) {
        unsigned sid[8];
        float ds[8];
        unsigned short u[8];
        #pragma unroll
        for (int j = 0; j < 8; ++j) sid[j] = csr4[beg + k + j];
        #pragma unroll
        for (int j = 0; j < 8; ++j) ds[j] = dinv[sid[j]];
        #pragma unroll
        for (int j = 0; j < 8; ++j) u[j] = h[(size_t)sid[j] * 64 + lane];
        #pragma unroll
        for (int j = 0; j < 8; ++j)
            acc += __uint_as_float((unsigned)u[j] << 16) * (di * ds[j]);
    }
    for (; k < cnt; ++k) {
        unsigned sid = csr4[beg + k];
        acc += __uint_as_float((unsigned)h[(size_t)sid * 64 + lane] << 16) * (di * dinv[sid]);
    }
    out[(size_t)i * 64 + lane] = acc + b2[lane];
}

extern "C" void kernel_launch(void* const* d_in, const int* in_sizes, int n_in,
                              void* d_out, int out_size, void* d_ws, size_t ws_size,
                              hipStream_t stream) {
    const float* x  = (const float*)d_in[0];
    const int*   ei = (const int*)d_in[1];
    const float* W1 = (const float*)d_in[2];
    const float* b1 = (const float*)d_in[3];
    const float* W2 = (const float*)d_in[4];
    const float* b2 = (const float*)d_in[5];
    float* out = (float*)d_out;

    const int N = in_sizes[0] / 128;
    const int E = in_sizes[1] / 2;
    const int* src = ei;
    const int* dst = ei + E;
    const int nbuck = (N + BSIZE - 1) >> BSHIFT;        // 196 for N=100000
    const size_t capE = (size_t)nbuck << CAPSH;         // padded edge capacity

    float* dinv     = (float*)d_ws;                     // N
    int*   deg      = (int*)(dinv + N);                 // N
    int*   row_ptr  = deg + N;                          // N
    int*   bcur     = row_ptr + N;                      // 256
    short* w1t      = (short*)(bcur + 256);             // 128*128
    short* w2t      = w1t + 128 * 128;                  // 64*128
    unsigned* csr4  = (unsigned*)(w2t + 64 * 128);      // capE (12.8 MB)
    short* bufH     = (short*)(csr4 + capE);            // N*128 bf16 (h1)
    short* bufH2    = bufH + (size_t)N * 128;           // N*64  bf16 (h2)
    unsigned* aggb  = (unsigned*)(bufH2 + (size_t)N * 64); // N*64 bf16x2 (agg1)
    unsigned* ebuf  = (unsigned*)bufH2;                 // capE uints; aliases
                                                        // bufH2+aggb (ebuf dead
                                                        // before their writes)

    const int ntile = (E + 4095) / 4096;

    // ---- weight prep + bucket cursor init (one launch) ----
    k_prep<<<97, 256, 0, stream>>>(W1, W2, w1t, w2t, bcur, nbuck);

    // ---- bucketed CSR build (per-node atomics all in LDS) ----
    k_bucket<<<ntile, 256, 0, stream>>>(src, dst, bcur, ebuf, E, nbuck);
    k_bcsr<<<nbuck, BSIZE, 0, stream>>>(ebuf, bcur, deg, row_ptr, dinv, csr4, N);

    // ---- layer 1 ----
    k_gemm1<<<(N + 63) / 64, 256, 0, stream>>>(x, w1t, bufH, N);
    k_pull128<<<(N + 3) / 4, 256, 0, stream>>>((const unsigned short*)bufH, row_ptr, deg, csr4, dinv, aggb, N);

    // ---- layer 2 ----
    k_gemm2<<<(N + 63) / 64, 256, 0, stream>>>(aggb, b1, w2t, bufH2, N);
    k_pull64<<<(N + 3) / 4, 256, 0, stream>>>((const unsigned short*)bufH2, row_ptr, deg, csr4, dinv, b2, out, N);
}

// Round 11
// 289.708 us; speedup vs baseline: 1.0592x; 1.0592x over previous
//
#include <hip/hip_runtime.h>
#include <hip/hip_bf16.h>

// GCN 2-layer forward, fp32 I/O. dinv folded into stored rows:
//   h1' = dinv * (x @ W1),  agg1 = dinv * (h1'[i] + sum_nbr h1'[s])
//   h2' = dinv * (relu(agg1+b1) @ W2),  out = dinv * (h2'[i] + sum h2'[s]) + b2
// so pull kernels are pure gather+add (no per-edge norm, no dinv reads).
// Packed 4B edge records; fixed-capacity bucketed CSR build with all
// per-node atomics in LDS; bf16 h/agg storage; MFMA bf16 GEMMs.
// Pipeline:
//  1) k_prep: W1,W2 -> bf16 transposed; bcur[b] = b*CAP
//  2) k_bucket: partition packed {src,dloc} by dst>>9 into ebuf
//  3) k_bcsr:  per-bucket LDS stage -> hist -> scan -> deg/dinv/row_ptr
//              -> LDS-cursor scatter -> csr4 = src
//  4) h1' = dinv*(x @ W1) -> bf16                  (k_gemm1, MFMA)
//  5) aggb = dinv*(self+gather-sum of h1') -> bf16 (k_pull128)
//  6) h2' = dinv*(relu(aggb+b1) @ W2) -> bf16      (k_gemm2, MFMA)
//  7) out = dinv*(self+gather-sum of h2') + b2     (k_pull64)

typedef short short8v __attribute__((ext_vector_type(8)));   // 8 bf16 (4 VGPRs)
typedef float f32x4   __attribute__((ext_vector_type(4)));   // MFMA acc

#define BSHIFT 9           // bucket = dst >> 9 (span 512 nodes)
#define BSIZE  512
#define CAPSH  14          // per-bucket capacity 16384 (mean 8163, >40 sigma)
#define CAP    (1 << CAPSH)

// RNE fp32 -> bf16 (finite inputs)
__device__ __forceinline__ short f2bf(float f) {
    unsigned u = __float_as_uint(f);
    return (short)((u + 0x7fffu + ((u >> 16) & 1u)) >> 16);
}
__device__ __forceinline__ unsigned pack2bf(float a, float b) {
    return (unsigned)(unsigned short)f2bf(a) | ((unsigned)(unsigned short)f2bf(b) << 16);
}
__device__ __forceinline__ float bflo(unsigned u) { return __uint_as_float(u << 16); }
__device__ __forceinline__ float bfhi(unsigned u) { return __uint_as_float(u & 0xffff0000u); }

// ---- W prep + bucket-cursor init (one launch) ----
__global__ void k_prep(const float* __restrict__ W1, const float* __restrict__ W2,
                       short* __restrict__ w1t, short* __restrict__ w2t,
                       int* __restrict__ bcur, int nbuck) {
    int b = blockIdx.x;
    int t = threadIdx.x;
    if (b == gridDim.x - 1) {                 // last block: init bucket cursors
        if (t < nbuck) bcur[t] = t << CAPSH;
        return;
    }
    int i = b * 256 + t;                      // 96 blocks cover 24576 elems
    if (i < 128 * 128) {
        int n = i >> 7, k = i & 127;
        w1t[i] = f2bf(W1[k * 128 + n]);
    } else {
        int j = i - 128 * 128;
        int n = j >> 7, k = j & 127;
        w2t[j] = f2bf(W2[k * 64 + n]);
    }
}

// ---- partition edges into packed ebuf: entry = (src<<9) | (dst&511) ----
__global__ __launch_bounds__(256) void k_bucket(const int* __restrict__ src,
                                                const int* __restrict__ dst,
                                                int* __restrict__ bcur,
                                                unsigned* __restrict__ ebuf,
                                                int E, int nbuck) {
    __shared__ int sdst[4096];
    __shared__ int ssrc[4096];
    __shared__ int hist[256];
    __shared__ int base[256];
    int t = threadIdx.x;
    int e0 = blockIdx.x * 4096;
    for (int i = t; i < nbuck; i += 256) hist[i] = 0;
    for (int i = 0; i < 16; ++i) {                  // single global read
        int k = i * 256 + t;
        int e = e0 + k;
        sdst[k] = (e < E) ? dst[e] : -1;
        ssrc[k] = (e < E) ? src[e] : 0;
    }
    __syncthreads();
    for (int i = 0; i < 16; ++i) {                  // pass 1: LDS histogram
        int d = sdst[i * 256 + t];
        if (d >= 0) atomicAdd(&hist[d >> BSHIFT], 1);
    }
    __syncthreads();
    for (int b = t; b < nbuck; b += 256) {          // pass 2: reserve chunks
        int c = hist[b];
        base[b] = c ? atomicAdd(&bcur[b], c) : 0;
        hist[b] = 0;
    }
    __syncthreads();
    for (int i = 0; i < 16; ++i) {                  // pass 3: grouped writes
        int k = i * 256 + t;
        int d = sdst[k];
        if (d >= 0) {
            int bk = d >> BSHIFT;
            int off = atomicAdd(&hist[bk], 1);
            ebuf[base[bk] + off] = ((unsigned)ssrc[k] << BSHIFT) | (unsigned)(d & (BSIZE - 1));
        }
    }
}

// ---- per-bucket merged: LDS stage -> hist -> scan -> deg/dinv/row_ptr
//      -> LDS-cursor scatter -> csr4 = src ----
__global__ __launch_bounds__(BSIZE) void k_bcsr(const unsigned* __restrict__ ebuf,
                                                const int* __restrict__ bcur,
                                                int* __restrict__ deg,
                                                int* __restrict__ row_ptr,
                                                float* __restrict__ dinv,
                                                unsigned* __restrict__ csr4, int n) {
    __shared__ unsigned edges[CAP];    // 64 KB
    __shared__ int hist[BSIZE];
    __shared__ int s[BSIZE];
    __shared__ int cur[BSIZE];
    int b = blockIdx.x;
    int t = threadIdx.x;
    hist[t] = 0;
    __syncthreads();
    int base = b << CAPSH;
    int cnt  = bcur[b] - base;
    int lo = b << BSHIFT;
    for (int k = t; k < cnt; k += BSIZE) {          // stage + LDS hist
        unsigned e = ebuf[base + k];
        edges[k] = e;
        atomicAdd(&hist[e & (BSIZE - 1)], 1);
    }
    __syncthreads();
    int v = hist[t];
    s[t] = v;
    __syncthreads();
    for (int off = 1; off < BSIZE; off <<= 1) {     // inclusive scan
        int add = (t >= off) ? s[t - off] : 0;
        __syncthreads();
        s[t] += add;
        __syncthreads();
    }
    int rp = base + s[t] - v;                       // padded-CSR offset
    cur[t] = rp;
    int node = lo + t;
    if (node < n) {
        deg[node]     = v;
        row_ptr[node] = rp;
        dinv[node]    = rsqrtf((float)(v + 1));
    }
    __syncthreads();
    for (int k = t; k < cnt; k += BSIZE) {          // scatter src -> csr4
        unsigned e = edges[k];
        int pos = atomicAdd(&cur[e & (BSIZE - 1)], 1);
        csr4[pos] = e >> BSHIFT;
    }
}

// ---- MFMA GEMM1: h1'[64rows,128] = dinv*(bf16(x) @ bf16(W1)) ----
#define LDP 136
__global__ __launch_bounds__(256) void k_gemm1(const float* __restrict__ x,
                                               const short* __restrict__ w1t,
                                               const float* __restrict__ dinv,
                                               short* __restrict__ h, int nrows) {
    __shared__ short xs[64 * LDP];
    __shared__ short wt[128 * LDP];
    int t = threadIdx.x;
    int row0 = blockIdx.x * 64;
    for (int i = 0; i < 16; ++i) {
        int idx = t + i * 256;
        int r = idx >> 5, c4 = idx & 31;
        float4 v = make_float4(0.f, 0.f, 0.f, 0.f);
        if (row0 + r < nrows) v = ((const float4*)x)[(size_t)(row0 + r) * 32 + c4];
        short4 o = make_short4(f2bf(v.x), f2bf(v.y), f2bf(v.z), f2bf(v.w));
        *(short4*)&xs[r * LDP + c4 * 4] = o;
    }
    for (int i = 0; i < 16; ++i) {
        int idx = t + i * 256;
        int n = idx >> 5, c4 = idx & 31;
        *(short4*)&wt[n * LDP + c4 * 4] = ((const short4*)w1t)[idx];
    }
    __syncthreads();
    int wave = t >> 6, lane = t & 63;
    int quad = lane >> 4, c = lane & 15;
    int m0 = wave * 16;
    f32x4 acc[8] = {};
    #pragma unroll
    for (int kc = 0; kc < 4; ++kc) {
        short8v a = *(const short8v*)&xs[(m0 + c) * LDP + kc * 32 + quad * 8];
        #pragma unroll
        for (int nt = 0; nt < 8; ++nt) {
            short8v b = *(const short8v*)&wt[(nt * 16 + c) * LDP + kc * 32 + quad * 8];
            acc[nt] = __builtin_amdgcn_mfma_f32_16x16x32_bf16(a, b, acc[nt], 0, 0, 0);
        }
    }
    #pragma unroll
    for (int r = 0; r < 4; ++r) {
        int row = row0 + m0 + quad * 4 + r;
        if (row < nrows) {
            float dr = dinv[row];                   // fold norm into stored row
            #pragma unroll
            for (int nt = 0; nt < 8; ++nt)
                h[(size_t)row * 128 + nt * 16 + c] = f2bf(acc[nt][r] * dr);
        }
    }
}

// ---- MFMA GEMM2: h2'[64rows,64] = dinv*(bf16(relu(aggb+b1)) @ bf16(W2)) ----
__global__ __launch_bounds__(256) void k_gemm2(const unsigned* __restrict__ aggb, // bf16x2
                                               const float* __restrict__ b1,
                                               const short* __restrict__ w2t,
                                               const float* __restrict__ dinv,
                                               short* __restrict__ h2, int nrows) {
    __shared__ short xs[64 * LDP];
    __shared__ short wt[64 * LDP];
    int t = threadIdx.x;
    int row0 = blockIdx.x * 64;
    for (int i = 0; i < 16; ++i) {                    // 64 rows x 64 bf16-pairs
        int idx = t + i * 256;
        int r = idx >> 6, cp = idx & 63;
        unsigned o = 0;
        if (row0 + r < nrows) {
            unsigned u = aggb[(size_t)(row0 + r) * 64 + cp];
            float2 bb = ((const float2*)b1)[cp];
            float vx = fmaxf(bflo(u) + bb.x, 0.f);
            float vy = fmaxf(bfhi(u) + bb.y, 0.f);
            o = pack2bf(vx, vy);
        }
        *(unsigned*)&xs[r * LDP + cp * 2] = o;
    }
    for (int i = 0; i < 8; ++i) {
        int idx = t + i * 256;
        int n = idx >> 5, c4 = idx & 31;
        *(short4*)&wt[n * LDP + c4 * 4] = ((const short4*)w2t)[idx];
    }
    __syncthreads();
    int wave = t >> 6, lane = t & 63;
    int quad = lane >> 4, c = lane & 15;
    int m0 = wave * 16;
    f32x4 acc[4] = {};
    #pragma unroll
    for (int kc = 0; kc < 4; ++kc) {
        short8v av = *(const short8v*)&xs[(m0 + c) * LDP + kc * 32 + quad * 8];
        #pragma unroll
        for (int nt = 0; nt < 4; ++nt) {
            short8v b = *(const short8v*)&wt[(nt * 16 + c) * LDP + kc * 32 + quad * 8];
            acc[nt] = __builtin_amdgcn_mfma_f32_16x16x32_bf16(av, b, acc[nt], 0, 0, 0);
        }
    }
    #pragma unroll
    for (int r = 0; r < 4; ++r) {
        int row = row0 + m0 + quad * 4 + r;
        if (row < nrows) {
            float dr = dinv[row];
            #pragma unroll
            for (int nt = 0; nt < 4; ++nt)
                h2[(size_t)row * 64 + nt * 16 + c] = f2bf(acc[nt][r] * dr);
        }
    }
}

// pull 128 feats: aggb[i] = bf16( dinv[i] * (h'[i] + sum_nbr h'[s]) ).
// One wave/node; pure gather+add inner loop (csr reads on scalar path).
__global__ __launch_bounds__(256) void k_pull128(const unsigned short* __restrict__ h,
                                                 const int* __restrict__ row_ptr,
                                                 const int* __restrict__ deg,
                                                 const unsigned* __restrict__ csr4,
                                                 const float* __restrict__ dinv,
                                                 unsigned* __restrict__ aggb, int n) {
    int wave = (blockIdx.x * 256 + threadIdx.x) >> 6;
    int lane = threadIdx.x & 63;
    if (wave >= n) return;
    int i = __builtin_amdgcn_readfirstlane(wave);
    float2 acc;
    {
        unsigned u = ((const unsigned*)(h + (size_t)i * 128))[lane];   // self
        acc.x = bflo(u);
        acc.y = bfhi(u);
    }
    int beg = row_ptr[i];
    int cnt = deg[i];
    int k = 0;
    for (; k + 8 <= cnt; k += 8) {
        unsigned sid[8];
        unsigned g[8];
        #pragma unroll
        for (int j = 0; j < 8; ++j) sid[j] = csr4[beg + k + j];
        #pragma unroll
        for (int j = 0; j < 8; ++j)
            g[j] = ((const unsigned*)(h + (size_t)sid[j] * 128))[lane];
        #pragma unroll
        for (int j = 0; j < 8; ++j) {
            acc.x += bflo(g[j]);
            acc.y += bfhi(g[j]);
        }
    }
    for (; k < cnt; ++k) {
        unsigned sid = csr4[beg + k];
        unsigned g = ((const unsigned*)(h + (size_t)sid * 128))[lane];
        acc.x += bflo(g);
        acc.y += bfhi(g);
    }
    float di = dinv[i];
    aggb[(size_t)i * 64 + lane] = pack2bf(acc.x * di, acc.y * di);
}

// pull 64 feats: out[i] = dinv[i]*(h'[i] + sum h'[s]) + b2. One wave/node.
__global__ __launch_bounds__(256) void k_pull64(const unsigned short* __restrict__ h,
                                                const int* __restrict__ row_ptr,
                                                const int* __restrict__ deg,
                                                const unsigned* __restrict__ csr4,
                                                const float* __restrict__ dinv,
                                                const float* __restrict__ b2,
                                                float* __restrict__ out, int n) {
    int wave = (blockIdx.x * 256 + threadIdx.x) >> 6;
    int lane = threadIdx.x & 63;
    if (wave >= n) return;
    int i = __builtin_amdgcn_readfirstlane(wave);
    float acc = __uint_as_float((unsigned)h[(size_t)i * 64 + lane] << 16);  // self
    int beg = row_ptr[i];
    int cnt = deg[i];
    int k = 0;
    for (; k + 8 <= cnt; k += 8) {
        unsigned sid[8];
        unsigned short u[8];
        #pragma unroll
        for (int j = 0; j < 8; ++j) sid[j] = csr4[beg + k + j];
        #pragma unroll
        for (int j = 0; j < 8; ++j) u[j] = h[(size_t)sid[j] * 64 + lane];
        #pragma unroll
        for (int j = 0; j < 8; ++j)
            acc += __uint_as_float((unsigned)u[j] << 16);
    }
    for (; k < cnt; ++k) {
        unsigned sid = csr4[beg + k];
        acc += __uint_as_float((unsigned)h[(size_t)sid * 64 + lane] << 16);
    }
    out[(size_t)i * 64 + lane] = acc * dinv[i] + b2[lane];
}

extern "C" void kernel_launch(void* const* d_in, const int* in_sizes, int n_in,
                              void* d_out, int out_size, void* d_ws, size_t ws_size,
                              hipStream_t stream) {
    const float* x  = (const float*)d_in[0];
    const int*   ei = (const int*)d_in[1];
    const float* W1 = (const float*)d_in[2];
    const float* b1 = (const float*)d_in[3];
    const float* W2 = (const float*)d_in[4];
    const float* b2 = (const float*)d_in[5];
    float* out = (float*)d_out;

    const int N = in_sizes[0] / 128;
    const int E = in_sizes[1] / 2;
    const int* src = ei;
    const int* dst = ei + E;
    const int nbuck = (N + BSIZE - 1) >> BSHIFT;        // 196 for N=100000
    const size_t capE = (size_t)nbuck << CAPSH;         // padded edge capacity

    float* dinv     = (float*)d_ws;                     // N
    int*   deg      = (int*)(dinv + N);                 // N
    int*   row_ptr  = deg + N;                          // N
    int*   bcur     = row_ptr + N;                      // 256
    short* w1t      = (short*)(bcur + 256);             // 128*128
    short* w2t      = w1t + 128 * 128;                  // 64*128
    unsigned* csr4  = (unsigned*)(w2t + 64 * 128);      // capE (12.8 MB)
    short* bufH     = (short*)(csr4 + capE);            // N*128 bf16 (h1')
    short* bufH2    = bufH + (size_t)N * 128;           // N*64  bf16 (h2')
    unsigned* aggb  = (unsigned*)(bufH2 + (size_t)N * 64); // N*64 bf16x2 (agg1)
    unsigned* ebuf  = (unsigned*)bufH2;                 // capE uints; aliases
                                                        // bufH2+aggb (ebuf dead
                                                        // before their writes)

    const int ntile = (E + 4095) / 4096;

    // ---- weight prep + bucket cursor init ----
    k_prep<<<97, 256, 0, stream>>>(W1, W2, w1t, w2t, bcur, nbuck);

    // ---- bucketed CSR build (per-node atomics all in LDS) ----
    k_bucket<<<ntile, 256, 0, stream>>>(src, dst, bcur, ebuf, E, nbuck);
    k_bcsr<<<nbuck, BSIZE, 0, stream>>>(ebuf, bcur, deg, row_ptr, dinv, csr4, N);

    // ---- layer 1 ----
    k_gemm1<<<(N + 63) / 64, 256, 0, stream>>>(x, w1t, dinv, bufH, N);
    k_pull128<<<(N + 3) / 4, 256, 0, stream>>>((const unsigned short*)bufH, row_ptr, deg, csr4, dinv, aggb, N);

    // ---- layer 2 ----
    k_gemm2<<<(N + 63) / 64, 256, 0, stream>>>(aggb, b1, w2t, dinv, bufH2, N);
    k_pull64<<<(N + 3) / 4, 256, 0, stream>>>((const unsigned short*)bufH2, row_ptr, deg, csr4, dinv, b2, out, N);
}